// Round 8
// baseline (118.280 us; speedup 1.0000x reference)
//
#include <hip/hip_runtime.h>
#include <math.h>

#pragma clang fp contract(off)

#define TILE 16
#define CELLPX 32
#define LCAP 896       // per-cell ordered list capacity (u16)
#define MAXS 256       // bake scan depth = one LDS batch

// rec (16 dwords): [0]=bx [1]=by [2]=cx-bx [3]=cy-by | [4]=cx [5]=cy [6]=ax-cx [7]=ay-cy
//                  [8]=ax [9]=ay [10]=bx-ax [11]=by-ay | [12]=inv(0 if invalid) [13..15]=i0,i1,i2
__global__ __launch_bounds__(256) void prep(
    const float* __restrict__ uv, const int* __restrict__ faces,
    float* __restrict__ recs, unsigned long long* __restrict__ bitmap,
    int nTri, int nBitWords)
{
    for (int i = blockIdx.x * 256 + threadIdx.x; i < nBitWords; i += gridDim.x * 256)
        bitmap[i] = 0ull;
    const int f = blockIdx.x * 256 + threadIdx.x;
    if (f >= nTri) return;
    const int i0 = faces[3 * f], i1 = faces[3 * f + 1], i2 = faces[3 * f + 2];
    const float ax = uv[2 * i0], ay = uv[2 * i0 + 1];
    const float bx = uv[2 * i1], by = uv[2 * i1 + 1];
    const float cx = uv[2 * i2], cy = uv[2 * i2 + 1];
    const float area = (bx - ax) * (cy - ay) - (by - ay) * (cx - ax);  // exact ref op
    const bool valid = fabsf(area) > 1e-9f;
    float* r = recs + 16 * f;
    r[0] = bx; r[1] = by; r[2]  = cx - bx; r[3]  = cy - by;
    r[4] = cx; r[5] = cy; r[6]  = ax - cx; r[7]  = ay - cy;
    r[8] = ax; r[9] = ay; r[10] = bx - ax; r[11] = by - ay;
    r[12] = valid ? 1.0f / area : 0.f;
    ((int*)r)[13] = i0; ((int*)r)[14] = i1; ((int*)r)[15] = i2;
}

__device__ __forceinline__ bool edgeMayPass(
    float qx, float qy, float ex, float ey, float s,
    float rx0, float rx1, float ry0, float ry1)
{
    const float A = s * ex;
    const float B = -s * ey;
    const float fy = A * ((A >= 0.f ? ry1 : ry0) - qy);
    const float fx = B * ((B >= 0.f ? rx1 : rx0) - qx);
    return (fy + fx) >= -1e-5f;   // conservative margin >> fp eval error
}

__device__ __forceinline__ bool satKeep(
    const float4 r0, const float4 r1, const float4 r2, const float inv,
    float rx0, float rx1, float ry0, float ry1)
{
    if (inv == 0.f) return false;
    const float xmn = fminf(r2.x, fminf(r0.x, r1.x));
    const float xmx = fmaxf(r2.x, fmaxf(r0.x, r1.x));
    const float ymn = fminf(r2.y, fminf(r0.y, r1.y));
    const float ymx = fmaxf(r2.y, fmaxf(r0.y, r1.y));
    if (!((xmn <= rx1) & (xmx >= rx0) & (ymn <= ry1) & (ymx >= ry0))) return false;
    const float s = (inv >= 0.f) ? 1.f : -1.f;
    return edgeMayPass(r0.x, r0.y, r0.z, r0.w, s, rx0, rx1, ry0, ry1)
        && edgeMayPass(r1.x, r1.y, r1.z, r1.w, s, rx0, rx1, ry0, ry1)
        && edgeMayPass(r2.x, r2.y, r2.z, r2.w, s, rx0, rx1, ry0, ry1);
}

// One block per 32px cell; scans triangles in index order -> globally ordered list.
__global__ __launch_bounds__(256) void bin32(
    const float* __restrict__ recs, unsigned short* __restrict__ lists,
    int* __restrict__ counts, int res, int nTri, int nCellX)
{
    __shared__ int waveCnt[4];
    const int cell = blockIdx.x;
    const int cellX = cell % nCellX, cellY = cell / nCellX;
    const float rf = (float)res;
    const float rx0 = ((float)(cellX * CELLPX) - 1.5f) / rf;
    const float rx1 = ((float)(cellX * CELLPX + CELLPX) + 1.5f) / rf;
    const float ry0 = ((float)(cellY * CELLPX) - 1.5f) / rf;
    const float ry1 = ((float)(cellY * CELLPX + CELLPX) + 1.5f) / rf;

    const int lane = threadIdx.x & 63, wv = threadIdx.x >> 6;
    unsigned short* myList = lists + (size_t)cell * LCAP;

    int cnt = 0;
    for (int base = 0; base < nTri; base += 256) {
        const int t = base + threadIdx.x;
        bool keep = false;
        if (t < nTri) {
            const float4* R = (const float4*)(recs + 16 * t);   // coalesced 64B/lane
            const float4 r0 = R[0], r1 = R[1], r2 = R[2], r3 = R[3];
            keep = satKeep(r0, r1, r2, r3.x, rx0, rx1, ry0, ry1);
        }
        const unsigned long long m = __ballot(keep);
        if (lane == 0) waveCnt[wv] = __popcll(m);
        __syncthreads();
        int off = 0;
        #pragma unroll
        for (int w = 0; w < 4; ++w) if (w < wv) off += waveCnt[w];
        const int tot = waveCnt[0] + waveCnt[1] + waveCnt[2] + waveCnt[3];
        const int pre = __popcll(m & ((1ull << lane) - 1ull));
        if (keep) {
            const int slot = cnt + off + pre;
            if (slot < LCAP) myList[slot] = (unsigned short)t;
        }
        __syncthreads();
        cnt += tot;   // > LCAP => cell uses ordered range-scan instead
    }
    if (threadIdx.x == 0) counts[cell] = cnt;
}

// One 16px tile per block. Exactly ONE 256-candidate LDS batch; leftovers -> bitmap.
__global__ __launch_bounds__(256) void bake16(
    const float* __restrict__ recs, const unsigned short* __restrict__ lists,
    const int* __restrict__ counts, const float* __restrict__ attr,
    float* __restrict__ out, unsigned long long* __restrict__ bitmap,
    int res, int nTri, int nCellX)
{
    __shared__ float4 L0[MAXS], L1[MAXS], L2[MAXS], L3[MAXS];
    __shared__ unsigned long long smask[4];

    const int tx = threadIdx.x & 15, ty = threadIdx.x >> 4;
    const int pxi = blockIdx.x * TILE + tx;
    const int pyi = blockIdx.y * TILE + ty;
    const bool inb = (pxi < res) && (pyi < res);
    const float rf = (float)res;
    const float px = ((float)pxi + 0.5f) / rf;   // exact reference op
    const float py = ((float)pyi + 0.5f) / rf;

    const int cell = ((blockIdx.y * TILE) / CELLPX) * nCellX + (blockIdx.x * TILE) / CELLPX;
    const int count = counts[cell];
    const bool useList = (count <= LCAP);
    const int total = useList ? count : nTri;
    const int n = min(MAXS, total);

    const int lane = threadIdx.x & 63, wv = threadIdx.x >> 6;

    // ---- fill one batch + per-candidate sign-of-inv mask ----
    bool sb = false;
    if (threadIdx.x < n) {
        const int t = useList ? (int)lists[(size_t)cell * LCAP + threadIdx.x] : threadIdx.x;
        const float4* R = (const float4*)(recs + 16 * t);
        float4 r0 = R[0];
        const float4 r1 = R[1], r2 = R[2], r3 = R[3];
        sb = (__float_as_uint(r3.x) >> 31) != 0;
        if (r3.x == 0.f)   // invalid tri: poison edge0 -> w0=-inf, sbit mismatch -> never passes
            r0 = make_float4(0.f, __builtin_huge_valf(), 1.f, 0.f);
        L0[threadIdx.x] = r0; L1[threadIdx.x] = r1; L2[threadIdx.x] = r2; L3[threadIdx.x] = r3;
    }
    const unsigned long long bal = __ballot(sb);
    if (lane == 0) smask[wv] = bal;
    __syncthreads();
    const unsigned long long m0 = smask[0], m1 = smask[1], m2 = smask[2], m3 = smask[3];

    // ---- ordered scan, sign test only (3 LDS reads/candidate) ----
    bool hit = false; int kWin = 0;
    if (inb) {
        const int last = n - 1;
        for (int i = 0; i < n && !hit; i += 4) {
            const int ka = i, kb = min(i + 1, last), kc = min(i + 2, last), kd = min(i + 3, last);
            const float4 A0 = L0[ka], A1 = L1[ka], A2 = L2[ka];
            const float4 B0 = L0[kb], B1 = L1[kb], B2 = L2[kb];
            const float4 C0 = L0[kc], C1 = L1[kc], C2 = L2[kc];
            const float4 D0 = L0[kd], D1 = L1[kd], D2 = L2[kd];
            const unsigned long long mw = (i & 128) ? ((i & 64) ? m3 : m2)
                                                    : ((i & 64) ? m1 : m0);
            #define TST(Q0, Q1, Q2, KK)                                               \
                if (!hit) {                                                           \
                    const float w0 = Q0.z * (py - Q0.y) - Q0.w * (px - Q0.x);         \
                    const float w1 = Q1.z * (py - Q1.y) - Q1.w * (px - Q1.x);         \
                    const float w2 = Q2.z * (py - Q2.y) - Q2.w * (px - Q2.x);         \
                    const unsigned sv = (unsigned)((mw >> (KK & 63)) & 1ull);         \
                    const bool p0 = (w0 == 0.f) | ((__float_as_uint(w0) >> 31) == sv);\
                    const bool p1 = (w1 == 0.f) | ((__float_as_uint(w1) >> 31) == sv);\
                    const bool p2 = (w2 == 0.f) | ((__float_as_uint(w2) >> 31) == sv);\
                    if (p0 & p1 & p2) { hit = true; kWin = KK; }                      \
                }
            TST(A0, A1, A2, ka)
            TST(B0, B1, B2, kb)
            TST(C0, C1, C2, kc)
            TST(D0, D1, D2, kd)
            #undef TST
        }
    }

    if (inb) {
        if (hit) {   // recompute exact reference barycentrics for the winner
            const float4 E0 = L0[kWin], E1 = L1[kWin], E2 = L2[kWin], E3 = L3[kWin];
            const float w0 = E0.z * (py - E0.y) - E0.w * (px - E0.x);
            const float w1 = E1.z * (py - E1.y) - E1.w * (px - E1.x);
            const float w2 = E2.z * (py - E2.y) - E2.w * (px - E2.x);
            const float iv = E3.x;
            const float g0 = w0 * iv, g1 = w1 * iv, g2 = w2 * iv;
            const int i0 = __float_as_int(E3.y), i1 = __float_as_int(E3.z), i2 = __float_as_int(E3.w);
            const int o = (pyi * res + pxi) * 3;
            out[o + 0] = g0 * attr[3 * i0 + 0] + g1 * attr[3 * i1 + 0] + g2 * attr[3 * i2 + 0];
            out[o + 1] = g0 * attr[3 * i0 + 1] + g1 * attr[3 * i1 + 1] + g2 * attr[3 * i2 + 1];
            out[o + 2] = g0 * attr[3 * i0 + 2] + g1 * attr[3 * i1 + 2] + g2 * attr[3 * i2 + 2];
        } else if (total <= MAXS) {   // scanned the full (complete) list: truly empty
            const int o = (pyi * res + pxi) * 3;
            out[o + 0] = 0.f; out[o + 1] = 0.f; out[o + 2] = 0.f;
        } else {                      // defer to rescue (deterministic: idempotent OR)
            const int pid = pyi * res + pxi;
            atomicOr(&bitmap[pid >> 6], 1ull << (pid & 63));
        }
    }
}

// One wave per 64-pixel bitmap word; ballot-scan the list tail 64 candidates/iter.
__global__ __launch_bounds__(256) void rescue(
    const float* __restrict__ recs, const unsigned short* __restrict__ lists,
    const int* __restrict__ counts, const float* __restrict__ attr,
    float* __restrict__ out, const unsigned long long* __restrict__ bitmap,
    int res, int nTri, int nCellX, int nBitWords)
{
    const int lane = threadIdx.x & 63, wv = threadIdx.x >> 6;
    const float rf = (float)res;
    for (int w = blockIdx.x * 4 + wv; w < nBitWords; w += gridDim.x * 4) {
        unsigned long long mask = bitmap[w];
        while (mask) {
            const int b = __builtin_ctzll(mask);
            mask &= mask - 1;
            const int pid = w * 64 + b;
            const int pyi = pid / res, pxi = pid - pyi * res;
            const float px = ((float)pxi + 0.5f) / rf;
            const float py = ((float)pyi + 0.5f) / rf;
            const int cell = (pyi / CELLPX) * nCellX + pxi / CELLPX;
            const int count = counts[cell];
            const bool useList = (count <= LCAP);
            const int total = useList ? count : nTri;
            bool found = false;
            for (int base = MAXS; base < total && !found; base += 64) {
                const int idx = base + lane;
                bool pass = false;
                float g0 = 0.f, g1 = 0.f, g2 = 0.f; int i0 = 0, i1 = 0, i2 = 0;
                if (idx < total) {
                    const int t = useList ? (int)lists[(size_t)cell * LCAP + idx] : idx;
                    const float4* R = (const float4*)(recs + 16 * t);
                    const float4 r0 = R[0], r1 = R[1], r2 = R[2], r3 = R[3];
                    const float iv = r3.x;
                    if (iv != 0.f) {
                        const float w0 = r0.z * (py - r0.y) - r0.w * (px - r0.x);
                        const float w1 = r1.z * (py - r1.y) - r1.w * (px - r1.x);
                        const float w2 = r2.z * (py - r2.y) - r2.w * (px - r2.x);
                        const float b0 = w0 * iv, b1 = w1 * iv, b2 = w2 * iv;
                        if ((b0 >= 0.f) & (b1 >= 0.f) & (b2 >= 0.f)) {
                            pass = true; g0 = b0; g1 = b1; g2 = b2;
                            i0 = __float_as_int(r3.y); i1 = __float_as_int(r3.z); i2 = __float_as_int(r3.w);
                        }
                    }
                }
                const unsigned long long hm = __ballot(pass);
                if (hm) {
                    if (lane == (int)__builtin_ctzll(hm)) {
                        const int o = pid * 3;
                        out[o + 0] = g0 * attr[3 * i0 + 0] + g1 * attr[3 * i1 + 0] + g2 * attr[3 * i2 + 0];
                        out[o + 1] = g0 * attr[3 * i0 + 1] + g1 * attr[3 * i1 + 1] + g2 * attr[3 * i2 + 1];
                        out[o + 2] = g0 * attr[3 * i0 + 2] + g1 * attr[3 * i1 + 2] + g2 * attr[3 * i2 + 2];
                    }
                    found = true;
                }
            }
            if (!found && lane == 0) {
                const int o = pid * 3;
                out[o + 0] = 0.f; out[o + 1] = 0.f; out[o + 2] = 0.f;
            }
        }
    }
}

// ---- fallback (tiny workspace / huge nTri): proven-correct wave-per-pixel scan ----
__global__ __launch_bounds__(256) void bake_wave(
    const float* __restrict__ uv, const int* __restrict__ faces,
    const float* __restrict__ attr, float* __restrict__ out,
    int res, int nTri)
{
    const int lane = threadIdx.x & 63;
    const int wid  = blockIdx.x * (blockDim.x >> 6) + (threadIdx.x >> 6);
    const int npix = res * res;
    if (wid >= npix) return;
    const int pyi = wid / res, pxi = wid - pyi * res;
    const float rf = (float)res;
    const float px = ((float)pxi + 0.5f) / rf, py = ((float)pyi + 0.5f) / rf;
    for (int base = 0; base < nTri; base += 64) {
        const int t = base + lane;
        bool hit = false; float b0 = 0, b1 = 0, b2 = 0; int i0 = 0, i1 = 0, i2 = 0;
        if (t < nTri) {
            i0 = faces[3 * t]; i1 = faces[3 * t + 1]; i2 = faces[3 * t + 2];
            const float ax = uv[2 * i0], ay = uv[2 * i0 + 1];
            const float bx = uv[2 * i1], by = uv[2 * i1 + 1];
            const float cx = uv[2 * i2], cy = uv[2 * i2 + 1];
            const float area = (bx - ax) * (cy - ay) - (by - ay) * (cx - ax);
            if (fabsf(area) > 1e-9f) {
                const float inv = 1.0f / area;
                b0 = ((cx - bx) * (py - by) - (cy - by) * (px - bx)) * inv;
                b1 = ((ax - cx) * (py - cy) - (ay - cy) * (px - cx)) * inv;
                b2 = ((bx - ax) * (py - ay) - (by - ay) * (px - ax)) * inv;
                hit = (b0 >= 0.f) & (b1 >= 0.f) & (b2 >= 0.f);
            }
        }
        const unsigned long long m = __ballot(hit);
        if (m) {
            const int src = (int)__builtin_ctzll(m);
            b0 = __shfl(b0, src, 64); b1 = __shfl(b1, src, 64); b2 = __shfl(b2, src, 64);
            const int J0 = __shfl(i0, src, 64), J1 = __shfl(i1, src, 64), J2 = __shfl(i2, src, 64);
            if (lane == 0) {
                const int o = wid * 3;
                out[o + 0] = b0 * attr[3 * J0] + b1 * attr[3 * J1] + b2 * attr[3 * J2];
                out[o + 1] = b0 * attr[3 * J0 + 1] + b1 * attr[3 * J1 + 1] + b2 * attr[3 * J2 + 1];
                out[o + 2] = b0 * attr[3 * J0 + 2] + b1 * attr[3 * J1 + 2] + b2 * attr[3 * J2 + 2];
            }
            return;
        }
    }
    if (lane == 0) { const int o = wid * 3; out[o] = 0.f; out[o + 1] = 0.f; out[o + 2] = 0.f; }
}

extern "C" void kernel_launch(void* const* d_in, const int* in_sizes, int n_in,
                              void* d_out, int out_size, void* d_ws, size_t ws_size,
                              hipStream_t stream) {
    const float* attr  = (const float*)d_in[0];
    const float* uv    = (const float*)d_in[1];
    const int*   faces = (const int*)d_in[2];
    float*       out   = (float*)d_out;

    const int nTri = in_sizes[2] / 3;
    const int res  = (int)(sqrt((double)(out_size / 3)) + 0.5);
    const int npix = res * res;

    const int nCellX = (res + CELLPX - 1) / CELLPX;
    const int nCells = nCellX * nCellX;
    const int nBitWords = (npix + 63) / 64;

    const size_t recsB  = (size_t)nTri * 64;
    const size_t cntB   = (size_t)nCells * sizeof(int);
    const size_t listB  = (size_t)nCells * LCAP * sizeof(unsigned short);
    const size_t bmB    = (size_t)nBitWords * sizeof(unsigned long long);
    const size_t need   = recsB + cntB + listB + bmB;   // 1,016,832 B at 8192/512

    if (nTri <= 65535 && ws_size >= need) {
        char* p = (char*)d_ws;
        float* recs = (float*)p;                      p += recsB;
        int* counts = (int*)p;                        p += cntB;
        unsigned short* lists = (unsigned short*)p;   p += listB;
        unsigned long long* bitmap = (unsigned long long*)p;

        prep<<<(nTri + 255) / 256, 256, 0, stream>>>(uv, faces, recs, bitmap, nTri, nBitWords);
        bin32<<<nCells, 256, 0, stream>>>(recs, lists, counts, res, nTri, nCellX);
        dim3 grid((res + TILE - 1) / TILE, (res + TILE - 1) / TILE);
        bake16<<<grid, 256, 0, stream>>>(recs, lists, counts, attr, out, bitmap, res, nTri, nCellX);
        const int rblocks = min(1024, (nBitWords + 3) / 4);
        rescue<<<rblocks, 256, 0, stream>>>(recs, lists, counts, attr, out, bitmap,
                                            res, nTri, nCellX, nBitWords);
    } else {
        bake_wave<<<(npix + 3) / 4, 256, 0, stream>>>(uv, faces, attr, out, res, nTri);
    }
}

// Round 9
// 110.888 us; speedup vs baseline: 1.0667x; 1.0667x over previous
//
#include <hip/hip_runtime.h>
#include <math.h>

#pragma clang fp contract(off)

#define TILE 16
#define CELLPX 32
#define LCAP 2048      // per-cell ordered list capacity (u16); overflow -> raw-order scan
#define BATCH 256

// rec (16 dwords): [0]=bx [1]=by [2]=cx-bx [3]=cy-by | [4]=cx [5]=cy [6]=ax-cx [7]=ay-cy
//                  [8]=ax [9]=ay [10]=bx-ax [11]=by-ay | [12]=inv(0 if invalid) [13..15]=i0,i1,i2
__global__ __launch_bounds__(256) void prep(
    const float* __restrict__ uv, const int* __restrict__ faces,
    float* __restrict__ recs, int nTri)
{
    const int f = blockIdx.x * 256 + threadIdx.x;
    if (f >= nTri) return;
    const int i0 = faces[3 * f], i1 = faces[3 * f + 1], i2 = faces[3 * f + 2];
    const float ax = uv[2 * i0], ay = uv[2 * i0 + 1];
    const float bx = uv[2 * i1], by = uv[2 * i1 + 1];
    const float cx = uv[2 * i2], cy = uv[2 * i2 + 1];
    const float area = (bx - ax) * (cy - ay) - (by - ay) * (cx - ax);  // exact ref op
    const bool valid = fabsf(area) > 1e-9f;
    float* r = recs + 16 * f;
    r[0] = bx; r[1] = by; r[2]  = cx - bx; r[3]  = cy - by;
    r[4] = cx; r[5] = cy; r[6]  = ax - cx; r[7]  = ay - cy;
    r[8] = ax; r[9] = ay; r[10] = bx - ax; r[11] = by - ay;
    r[12] = valid ? 1.0f / area : 0.f;
    ((int*)r)[13] = i0; ((int*)r)[14] = i1; ((int*)r)[15] = i2;
}

__device__ __forceinline__ bool edgeMayPass(
    float qx, float qy, float ex, float ey, float s,
    float rx0, float rx1, float ry0, float ry1)
{
    const float A = s * ex;
    const float B = -s * ey;
    const float fy = A * ((A >= 0.f ? ry1 : ry0) - qy);
    const float fx = B * ((B >= 0.f ? rx1 : rx0) - qx);
    return (fy + fx) >= -1e-5f;   // conservative margin >> fp eval error
}

__device__ __forceinline__ bool satKeep(
    const float4 r0, const float4 r1, const float4 r2, const float inv,
    float rx0, float rx1, float ry0, float ry1)
{
    if (inv == 0.f) return false;
    const float xmn = fminf(r2.x, fminf(r0.x, r1.x));
    const float xmx = fmaxf(r2.x, fmaxf(r0.x, r1.x));
    const float ymn = fminf(r2.y, fminf(r0.y, r1.y));
    const float ymx = fmaxf(r2.y, fmaxf(r0.y, r1.y));
    if (!((xmn <= rx1) & (xmx >= rx0) & (ymn <= ry1) & (ymx >= ry0))) return false;
    const float s = (inv >= 0.f) ? 1.f : -1.f;
    return edgeMayPass(r0.x, r0.y, r0.z, r0.w, s, rx0, rx1, ry0, ry1)
        && edgeMayPass(r1.x, r1.y, r1.z, r1.w, s, rx0, rx1, ry0, ry1)
        && edgeMayPass(r2.x, r2.y, r2.z, r2.w, s, rx0, rx1, ry0, ry1);
}

// One 1024-thread block per 32px cell; index-order scan -> globally ordered list.
__global__ __launch_bounds__(1024) void bin32(
    const float* __restrict__ recs, unsigned short* __restrict__ lists,
    int* __restrict__ counts, int res, int nTri, int nCellX)
{
    __shared__ int waveCnt[16];
    const int cell = blockIdx.x;
    const int cellX = cell % nCellX, cellY = cell / nCellX;
    const float rf = (float)res;
    const float rx0 = ((float)(cellX * CELLPX) - 1.5f) / rf;
    const float rx1 = ((float)(cellX * CELLPX + CELLPX) + 1.5f) / rf;
    const float ry0 = ((float)(cellY * CELLPX) - 1.5f) / rf;
    const float ry1 = ((float)(cellY * CELLPX + CELLPX) + 1.5f) / rf;

    const int lane = threadIdx.x & 63, wv = threadIdx.x >> 6;
    unsigned short* myList = lists + (size_t)cell * LCAP;

    int cnt = 0;
    for (int base = 0; base < nTri; base += 1024) {
        const int t = base + threadIdx.x;
        bool keep = false;
        if (t < nTri) {
            const float4* R = (const float4*)(recs + 16 * t);   // coalesced 64B/lane
            const float4 r0 = R[0], r1 = R[1], r2 = R[2], r3 = R[3];
            keep = satKeep(r0, r1, r2, r3.x, rx0, rx1, ry0, ry1);
        }
        const unsigned long long m = __ballot(keep);
        if (lane == 0) waveCnt[wv] = __popcll(m);
        __syncthreads();
        int off = 0, tot = 0;
        #pragma unroll
        for (int w = 0; w < 16; ++w) {
            if (w < wv) off += waveCnt[w];
            tot += waveCnt[w];
        }
        const int pre = __popcll(m & ((1ull << lane) - 1ull));
        if (keep) {
            const int slot = cnt + off + pre;
            if (slot < LCAP) myList[slot] = (unsigned short)t;
        }
        __syncthreads();
        cnt += tot;   // > LCAP => bake uses raw-order scan (central cells: shallow hits)
    }
    if (threadIdx.x == 0) counts[cell] = cnt;
}

// One 16px tile per block; multi-batch LDS scan with next-batch register prefetch.
__global__ __launch_bounds__(256) void bake16(
    const float* __restrict__ recs, const unsigned short* __restrict__ lists,
    const int* __restrict__ counts, const float* __restrict__ attr,
    float* __restrict__ out, int res, int nTri, int nCellX)
{
    __shared__ float4 L0[BATCH], L1[BATCH], L2[BATCH], L3[BATCH];
    __shared__ unsigned long long smask[4];

    const int tx = threadIdx.x & 15, ty = threadIdx.x >> 4;
    const int pxi = blockIdx.x * TILE + tx;
    const int pyi = blockIdx.y * TILE + ty;
    const bool inb = (pxi < res) && (pyi < res);
    const float rf = (float)res;
    const float px = ((float)pxi + 0.5f) / rf;   // exact reference op
    const float py = ((float)pyi + 0.5f) / rf;

    const int cell = ((blockIdx.y * TILE) / CELLPX) * nCellX + (blockIdx.x * TILE) / CELLPX;
    const int count = counts[cell];              // uniform
    const bool useList = (count <= LCAP);
    const int total = useList ? count : nTri;
    const unsigned short* myList = lists + (size_t)cell * LCAP;

    const int lane = threadIdx.x & 63, wv = threadIdx.x >> 6;

    bool hit = false;
    float g0 = 0.f, g1 = 0.f, g2 = 0.f;
    int j0 = 0, j1 = 0, j2 = 0;

    // register prefetch of one batch
    float4 p0, p1, p2, p3;
    #define FETCH(POS)                                                        \
        {                                                                     \
            const int idx = (POS) + threadIdx.x;                              \
            if (idx < total) {                                                \
                const int t = useList ? (int)myList[idx] : idx;               \
                const float4* R = (const float4*)(recs + 16 * t);             \
                p0 = R[0]; p1 = R[1]; p2 = R[2]; p3 = R[3];                   \
            }                                                                 \
        }

    FETCH(0)
    for (int pos = 0; pos < total; pos += BATCH) {
        const int n = min(BATCH, total - pos);
        // ---- write batch to LDS + sign mask ----
        bool sb = false;
        if (threadIdx.x < n) {
            if (p3.x == 0.f)   // invalid tri (range mode only): poison -> never passes
                p0 = make_float4(0.f, __builtin_huge_valf(), 1.f, 0.f);
            sb = (__float_as_uint(p3.x) >> 31) != 0;
            L0[threadIdx.x] = p0; L1[threadIdx.x] = p1;
            L2[threadIdx.x] = p2; L3[threadIdx.x] = p3;
        }
        const unsigned long long bal = __ballot(sb);
        if (lane == 0) smask[wv] = bal;
        __syncthreads();
        const unsigned long long m0 = smask[0], m1 = smask[1],
                                 m2 = smask[2], m3 = smask[3];

        // ---- prefetch next batch (latency hidden under the scan) ----
        if (pos + BATCH < total) FETCH(pos + BATCH)

        // ---- ordered scan, sign test (3 broadcast LDS reads/candidate) ----
        if (inb && !hit) {
            const int last = n - 1;
            for (int i = 0; i < n; i += 4) {
                const int ka = i, kb = min(i + 1, last), kc = min(i + 2, last), kd = min(i + 3, last);
                const float4 A0 = L0[ka], A1 = L1[ka], A2 = L2[ka];
                const float4 B0 = L0[kb], B1 = L1[kb], B2 = L2[kb];
                const float4 C0 = L0[kc], C1 = L1[kc], C2 = L2[kc];
                const float4 D0 = L0[kd], D1 = L1[kd], D2 = L2[kd];
                const unsigned long long mw = (i & 128) ? ((i & 64) ? m3 : m2)
                                                        : ((i & 64) ? m1 : m0);
                #define TST(Q0, Q1, Q2, KK)                                                \
                    if (!hit) {                                                            \
                        const float w0 = Q0.z * (py - Q0.y) - Q0.w * (px - Q0.x);          \
                        const float w1 = Q1.z * (py - Q1.y) - Q1.w * (px - Q1.x);          \
                        const float w2 = Q2.z * (py - Q2.y) - Q2.w * (px - Q2.x);          \
                        const unsigned sv = (unsigned)((mw >> (KK & 63)) & 1ull);          \
                        const bool c0 = (w0 == 0.f) | ((__float_as_uint(w0) >> 31) == sv); \
                        const bool c1 = (w1 == 0.f) | ((__float_as_uint(w1) >> 31) == sv); \
                        const bool c2 = (w2 == 0.f) | ((__float_as_uint(w2) >> 31) == sv); \
                        if (c0 & c1 & c2) {                                                \
                            const float4 E3 = L3[KK];                                      \
                            const float iv = E3.x;                                         \
                            hit = true;                                                    \
                            g0 = w0 * iv; g1 = w1 * iv; g2 = w2 * iv;                      \
                            j0 = __float_as_int(E3.y);                                     \
                            j1 = __float_as_int(E3.z);                                     \
                            j2 = __float_as_int(E3.w);                                     \
                        }                                                                  \
                    }
                TST(A0, A1, A2, ka)
                TST(B0, B1, B2, kb)
                TST(C0, C1, C2, kc)
                TST(D0, D1, D2, kd)
                #undef TST
                if (hit) break;
            }
        }
        if (__syncthreads_and(hit || !inb)) break;   // also fences LDS reuse
    }

    if (inb) {
        float o0 = 0.f, o1 = 0.f, o2 = 0.f;
        if (hit) {
            o0 = g0 * attr[3 * j0 + 0] + g1 * attr[3 * j1 + 0] + g2 * attr[3 * j2 + 0];
            o1 = g0 * attr[3 * j0 + 1] + g1 * attr[3 * j1 + 1] + g2 * attr[3 * j2 + 1];
            o2 = g0 * attr[3 * j0 + 2] + g1 * attr[3 * j1 + 2] + g2 * attr[3 * j2 + 2];
        }
        const int o = (pyi * res + pxi) * 3;
        out[o + 0] = o0; out[o + 1] = o1; out[o + 2] = o2;
    }
    #undef FETCH
}

// ---- fallback (tiny workspace / huge nTri): proven-correct wave-per-pixel scan ----
__global__ __launch_bounds__(256) void bake_wave(
    const float* __restrict__ uv, const int* __restrict__ faces,
    const float* __restrict__ attr, float* __restrict__ out,
    int res, int nTri)
{
    const int lane = threadIdx.x & 63;
    const int wid  = blockIdx.x * (blockDim.x >> 6) + (threadIdx.x >> 6);
    const int npix = res * res;
    if (wid >= npix) return;
    const int pyi = wid / res, pxi = wid - pyi * res;
    const float rf = (float)res;
    const float px = ((float)pxi + 0.5f) / rf, py = ((float)pyi + 0.5f) / rf;
    for (int base = 0; base < nTri; base += 64) {
        const int t = base + lane;
        bool hit = false; float b0 = 0, b1 = 0, b2 = 0; int i0 = 0, i1 = 0, i2 = 0;
        if (t < nTri) {
            i0 = faces[3 * t]; i1 = faces[3 * t + 1]; i2 = faces[3 * t + 2];
            const float ax = uv[2 * i0], ay = uv[2 * i0 + 1];
            const float bx = uv[2 * i1], by = uv[2 * i1 + 1];
            const float cx = uv[2 * i2], cy = uv[2 * i2 + 1];
            const float area = (bx - ax) * (cy - ay) - (by - ay) * (cx - ax);
            if (fabsf(area) > 1e-9f) {
                const float inv = 1.0f / area;
                b0 = ((cx - bx) * (py - by) - (cy - by) * (px - bx)) * inv;
                b1 = ((ax - cx) * (py - cy) - (ay - cy) * (px - cx)) * inv;
                b2 = ((bx - ax) * (py - ay) - (by - ay) * (px - ax)) * inv;
                hit = (b0 >= 0.f) & (b1 >= 0.f) & (b2 >= 0.f);
            }
        }
        const unsigned long long m = __ballot(hit);
        if (m) {
            const int src = (int)__builtin_ctzll(m);
            b0 = __shfl(b0, src, 64); b1 = __shfl(b1, src, 64); b2 = __shfl(b2, src, 64);
            const int J0 = __shfl(i0, src, 64), J1 = __shfl(i1, src, 64), J2 = __shfl(i2, src, 64);
            if (lane == 0) {
                const int o = wid * 3;
                out[o + 0] = b0 * attr[3 * J0] + b1 * attr[3 * J1] + b2 * attr[3 * J2];
                out[o + 1] = b0 * attr[3 * J0 + 1] + b1 * attr[3 * J1 + 1] + b2 * attr[3 * J2 + 1];
                out[o + 2] = b0 * attr[3 * J0 + 2] + b1 * attr[3 * J1 + 2] + b2 * attr[3 * J2 + 2];
            }
            return;
        }
    }
    if (lane == 0) { const int o = wid * 3; out[o] = 0.f; out[o + 1] = 0.f; out[o + 2] = 0.f; }
}

extern "C" void kernel_launch(void* const* d_in, const int* in_sizes, int n_in,
                              void* d_out, int out_size, void* d_ws, size_t ws_size,
                              hipStream_t stream) {
    const float* attr  = (const float*)d_in[0];
    const float* uv    = (const float*)d_in[1];
    const int*   faces = (const int*)d_in[2];
    float*       out   = (float*)d_out;

    const int nTri = in_sizes[2] / 3;
    const int res  = (int)(sqrt((double)(out_size / 3)) + 0.5);
    const int npix = res * res;

    const int nCellX = (res + CELLPX - 1) / CELLPX;
    const int nCells = nCellX * nCellX;

    const size_t recsB = (size_t)nTri * 64;
    const size_t cntB  = (size_t)nCells * sizeof(int);
    const size_t listB = (size_t)nCells * LCAP * sizeof(unsigned short);
    const size_t need  = recsB + cntB + listB;   // 1,573,888 B at 8192 tris / 512 res

    if (nTri <= 65535 && ws_size >= need) {
        char* p = (char*)d_ws;
        float* recs = (float*)p;                    p += recsB;
        int* counts = (int*)p;                      p += cntB;
        unsigned short* lists = (unsigned short*)p;

        prep<<<(nTri + 255) / 256, 256, 0, stream>>>(uv, faces, recs, nTri);
        bin32<<<nCells, 1024, 0, stream>>>(recs, lists, counts, res, nTri, nCellX);
        dim3 grid((res + TILE - 1) / TILE, (res + TILE - 1) / TILE);
        bake16<<<grid, 256, 0, stream>>>(recs, lists, counts, attr, out, res, nTri, nCellX);
    } else {
        bake_wave<<<(npix + 3) / 4, 256, 0, stream>>>(uv, faces, attr, out, res, nTri);
    }
}

// Round 10
// 96.234 us; speedup vs baseline: 1.2291x; 1.1523x over previous
//
#include <hip/hip_runtime.h>
#include <math.h>

#pragma clang fp contract(off)

#define TILE 16
#define CELLPX 32
#define LCAP 2048      // per-cell ordered list capacity (u16); overflow -> raw-order scan
#define MAXS 256       // stage-1 scan depth = one LDS batch
#define SENTU 0x7FC0DEADu   // NaN payload: impossible as a real output (outputs are finite)

// rec (16 dwords): [0]=bx [1]=by [2]=cx-bx [3]=cy-by | [4]=cx [5]=cy [6]=ax-cx [7]=ay-cy
//                  [8]=ax [9]=ay [10]=bx-ax [11]=by-ay | [12]=inv(0 if invalid) [13..15]=i0,i1,i2
__global__ __launch_bounds__(256) void prep(
    const float* __restrict__ uv, const int* __restrict__ faces,
    float* __restrict__ recs, int nTri)
{
    const int f = blockIdx.x * 256 + threadIdx.x;
    if (f >= nTri) return;
    const int i0 = faces[3 * f], i1 = faces[3 * f + 1], i2 = faces[3 * f + 2];
    const float ax = uv[2 * i0], ay = uv[2 * i0 + 1];
    const float bx = uv[2 * i1], by = uv[2 * i1 + 1];
    const float cx = uv[2 * i2], cy = uv[2 * i2 + 1];
    const float area = (bx - ax) * (cy - ay) - (by - ay) * (cx - ax);  // exact ref op
    const bool valid = fabsf(area) > 1e-9f;
    float* r = recs + 16 * f;
    r[0] = bx; r[1] = by; r[2]  = cx - bx; r[3]  = cy - by;
    r[4] = cx; r[5] = cy; r[6]  = ax - cx; r[7]  = ay - cy;
    r[8] = ax; r[9] = ay; r[10] = bx - ax; r[11] = by - ay;
    r[12] = valid ? 1.0f / area : 0.f;
    ((int*)r)[13] = i0; ((int*)r)[14] = i1; ((int*)r)[15] = i2;
}

__device__ __forceinline__ bool edgeMayPass(
    float qx, float qy, float ex, float ey, float s,
    float rx0, float rx1, float ry0, float ry1)
{
    const float A = s * ex;
    const float B = -s * ey;
    const float fy = A * ((A >= 0.f ? ry1 : ry0) - qy);
    const float fx = B * ((B >= 0.f ? rx1 : rx0) - qx);
    return (fy + fx) >= -1e-5f;   // conservative margin >> fp eval error
}

__device__ __forceinline__ bool satKeep(
    const float4 r0, const float4 r1, const float4 r2, const float inv,
    float rx0, float rx1, float ry0, float ry1)
{
    if (inv == 0.f) return false;
    const float xmn = fminf(r2.x, fminf(r0.x, r1.x));
    const float xmx = fmaxf(r2.x, fmaxf(r0.x, r1.x));
    const float ymn = fminf(r2.y, fminf(r0.y, r1.y));
    const float ymx = fmaxf(r2.y, fmaxf(r0.y, r1.y));
    if (!((xmn <= rx1) & (xmx >= rx0) & (ymn <= ry1) & (ymx >= ry0))) return false;
    const float s = (inv >= 0.f) ? 1.f : -1.f;
    return edgeMayPass(r0.x, r0.y, r0.z, r0.w, s, rx0, rx1, ry0, ry1)
        && edgeMayPass(r1.x, r1.y, r1.z, r1.w, s, rx0, rx1, ry0, ry1)
        && edgeMayPass(r2.x, r2.y, r2.z, r2.w, s, rx0, rx1, ry0, ry1);
}

// One 1024-thread block per 32px cell; index-order scan -> globally ordered list.
__global__ __launch_bounds__(1024) void bin32(
    const float* __restrict__ recs, unsigned short* __restrict__ lists,
    int* __restrict__ counts, int res, int nTri, int nCellX)
{
    __shared__ int waveCnt[16];
    const int cell = blockIdx.x;
    const int cellX = cell % nCellX, cellY = cell / nCellX;
    const float rf = (float)res;
    const float rx0 = ((float)(cellX * CELLPX) - 1.5f) / rf;
    const float rx1 = ((float)(cellX * CELLPX + CELLPX) + 1.5f) / rf;
    const float ry0 = ((float)(cellY * CELLPX) - 1.5f) / rf;
    const float ry1 = ((float)(cellY * CELLPX + CELLPX) + 1.5f) / rf;

    const int lane = threadIdx.x & 63, wv = threadIdx.x >> 6;
    unsigned short* myList = lists + (size_t)cell * LCAP;

    int cnt = 0;
    for (int base = 0; base < nTri; base += 1024) {
        const int t = base + threadIdx.x;
        bool keep = false;
        if (t < nTri) {
            const float4* R = (const float4*)(recs + 16 * t);   // coalesced 64B/lane
            const float4 r0 = R[0], r1 = R[1], r2 = R[2], r3 = R[3];
            keep = satKeep(r0, r1, r2, r3.x, rx0, rx1, ry0, ry1);
        }
        const unsigned long long m = __ballot(keep);
        if (lane == 0) waveCnt[wv] = __popcll(m);
        __syncthreads();
        int off = 0, tot = 0;
        #pragma unroll
        for (int w = 0; w < 16; ++w) {
            if (w < wv) off += waveCnt[w];
            tot += waveCnt[w];
        }
        const int pre = __popcll(m & ((1ull << lane) - 1ull));
        if (keep) {
            const int slot = cnt + off + pre;
            if (slot < LCAP) myList[slot] = (unsigned short)t;
        }
        __syncthreads();
        cnt += tot;   // > LCAP => raw-order mode (central cells: shallow hits anyway)
    }
    if (threadIdx.x == 0) counts[cell] = cnt;
}

// Stage 1: one 16px tile per block, EXACTLY one 256-candidate LDS batch.
// Unresolved-with-more-candidates pixels get a sentinel in out (stage 2 fixes them).
__global__ __launch_bounds__(256) void bake16(
    const float* __restrict__ recs, const unsigned short* __restrict__ lists,
    const int* __restrict__ counts, const float* __restrict__ attr,
    float* __restrict__ out, int res, int nTri, int nCellX)
{
    __shared__ float4 L0[MAXS], L1[MAXS], L2[MAXS], L3[MAXS];
    __shared__ unsigned long long smask[4];

    const int tx = threadIdx.x & 15, ty = threadIdx.x >> 4;
    const int pxi = blockIdx.x * TILE + tx;
    const int pyi = blockIdx.y * TILE + ty;
    const bool inb = (pxi < res) && (pyi < res);
    const float rf = (float)res;
    const float px = ((float)pxi + 0.5f) / rf;   // exact reference op
    const float py = ((float)pyi + 0.5f) / rf;

    const int cell = ((blockIdx.y * TILE) / CELLPX) * nCellX + (blockIdx.x * TILE) / CELLPX;
    const int count = counts[cell];              // uniform
    const bool useList = (count <= LCAP);
    const int total = useList ? count : nTri;
    const int n = min(MAXS, total);
    const unsigned short* myList = lists + (size_t)cell * LCAP;

    const int lane = threadIdx.x & 63, wv = threadIdx.x >> 6;

    // ---- fill one batch + sign-of-inv mask ----
    bool sb = false;
    if (threadIdx.x < n) {
        const int t = useList ? (int)myList[threadIdx.x] : threadIdx.x;
        const float4* R = (const float4*)(recs + 16 * t);
        float4 r0 = R[0];
        const float4 r1 = R[1], r2 = R[2], r3 = R[3];
        sb = (__float_as_uint(r3.x) >> 31) != 0;
        if (r3.x == 0.f)   // invalid tri (raw mode): poison edge0 -> never passes
            r0 = make_float4(0.f, __builtin_huge_valf(), 1.f, 0.f);
        L0[threadIdx.x] = r0; L1[threadIdx.x] = r1;
        L2[threadIdx.x] = r2; L3[threadIdx.x] = r3;
    }
    const unsigned long long bal = __ballot(sb);
    if (lane == 0) smask[wv] = bal;
    __syncthreads();
    const unsigned long long m0 = smask[0], m1 = smask[1], m2 = smask[2], m3 = smask[3];

    // ---- ordered scan, sign test (3 broadcast LDS reads/candidate) ----
    bool hit = false;
    float g0 = 0.f, g1 = 0.f, g2 = 0.f;
    int j0 = 0, j1 = 0, j2 = 0;
    if (inb && n > 0) {
        const int last = n - 1;
        for (int i = 0; i < n; i += 4) {
            const int ka = i, kb = min(i + 1, last), kc = min(i + 2, last), kd = min(i + 3, last);
            const float4 A0 = L0[ka], A1 = L1[ka], A2 = L2[ka];
            const float4 B0 = L0[kb], B1 = L1[kb], B2 = L2[kb];
            const float4 C0 = L0[kc], C1 = L1[kc], C2 = L2[kc];
            const float4 D0 = L0[kd], D1 = L1[kd], D2 = L2[kd];
            const unsigned long long mw = (i & 128) ? ((i & 64) ? m3 : m2)
                                                    : ((i & 64) ? m1 : m0);
            #define TST(Q0, Q1, Q2, KK)                                                \
                if (!hit) {                                                            \
                    const float w0 = Q0.z * (py - Q0.y) - Q0.w * (px - Q0.x);          \
                    const float w1 = Q1.z * (py - Q1.y) - Q1.w * (px - Q1.x);          \
                    const float w2 = Q2.z * (py - Q2.y) - Q2.w * (px - Q2.x);          \
                    const unsigned sv = (unsigned)((mw >> (KK & 63)) & 1ull);          \
                    const bool c0 = (w0 == 0.f) | ((__float_as_uint(w0) >> 31) == sv); \
                    const bool c1 = (w1 == 0.f) | ((__float_as_uint(w1) >> 31) == sv); \
                    const bool c2 = (w2 == 0.f) | ((__float_as_uint(w2) >> 31) == sv); \
                    if (c0 & c1 & c2) {                                                \
                        const float4 E3 = L3[KK];                                      \
                        const float iv = E3.x;                                         \
                        hit = true;                                                    \
                        g0 = w0 * iv; g1 = w1 * iv; g2 = w2 * iv;                      \
                        j0 = __float_as_int(E3.y);                                     \
                        j1 = __float_as_int(E3.z);                                     \
                        j2 = __float_as_int(E3.w);                                     \
                    }                                                                  \
                }
            TST(A0, A1, A2, ka)
            TST(B0, B1, B2, kb)
            TST(C0, C1, C2, kc)
            TST(D0, D1, D2, kd)
            #undef TST
            if (hit) break;
        }
    }

    if (inb) {
        const int o = (pyi * res + pxi) * 3;
        if (hit) {
            out[o + 0] = g0 * attr[3 * j0 + 0] + g1 * attr[3 * j1 + 0] + g2 * attr[3 * j2 + 0];
            out[o + 1] = g0 * attr[3 * j0 + 1] + g1 * attr[3 * j1 + 1] + g2 * attr[3 * j2 + 1];
            out[o + 2] = g0 * attr[3 * j0 + 2] + g1 * attr[3 * j1 + 2] + g2 * attr[3 * j2 + 2];
        } else if (total <= MAXS) {      // complete list scanned: truly empty pixel
            out[o + 0] = 0.f; out[o + 1] = 0.f; out[o + 2] = 0.f;
        } else {                         // defer to stage 2
            const float s = __uint_as_float(SENTU);
            out[o + 0] = s; out[o + 1] = s; out[o + 2] = s;
        }
    }
}

// Stage 2: one wave per straggler pixel. Lanes probe hash-scattered pixels so
// boundary stragglers spread uniformly across waves; ballot-scan 64 cand/iter.
__global__ __launch_bounds__(256) void rescue(
    const float* __restrict__ recs, const unsigned short* __restrict__ lists,
    const int* __restrict__ counts, const float* __restrict__ attr,
    float* __restrict__ out, int res, int nTri, int nCellX,
    int npix, unsigned M)   // M = pow2 >= npix
{
    const int lane = threadIdx.x & 63;
    const int w = blockIdx.x * 4 + (threadIdx.x >> 6);
    const float rf = (float)res;

    const unsigned t0 = (unsigned)w * 64u + (unsigned)lane;
    if (t0 >= M) return;
    const unsigned p = (t0 * 2654435761u) & (M - 1u);   // odd mult: bijection mod 2^k
    bool sent = false;
    if (p < (unsigned)npix) sent = (__float_as_uint(out[3 * p]) == SENTU);
    unsigned long long mask = __ballot(sent);

    while (mask) {
        const int b = (int)__builtin_ctzll(mask);
        mask &= mask - 1;
        const unsigned tb = (unsigned)w * 64u + (unsigned)b;
        const int pid = (int)((tb * 2654435761u) & (M - 1u));   // uniform across wave
        const int pyi = pid / res, pxi = pid - pyi * res;
        const float px = ((float)pxi + 0.5f) / rf;
        const float py = ((float)pyi + 0.5f) / rf;
        const int cell = (pyi / CELLPX) * nCellX + pxi / CELLPX;
        const int count = counts[cell];
        const bool useList = (count <= LCAP);
        const int total = useList ? count : nTri;
        const unsigned short* myList = lists + (size_t)cell * LCAP;

        bool found = false;
        for (int base = MAXS; base < total && !found; base += 64) {
            const int idx = base + lane;
            bool pass = false;
            float g0 = 0.f, g1 = 0.f, g2 = 0.f; int i0 = 0, i1 = 0, i2 = 0;
            if (idx < total) {
                const int t = useList ? (int)myList[idx] : idx;
                const float4* R = (const float4*)(recs + 16 * t);
                const float4 r0 = R[0], r1 = R[1], r2 = R[2], r3 = R[3];
                const float iv = r3.x;
                if (iv != 0.f) {
                    const float w0 = r0.z * (py - r0.y) - r0.w * (px - r0.x);
                    const float w1 = r1.z * (py - r1.y) - r1.w * (px - r1.x);
                    const float w2 = r2.z * (py - r2.y) - r2.w * (px - r2.x);
                    const float b0 = w0 * iv, b1 = w1 * iv, b2 = w2 * iv;
                    if ((b0 >= 0.f) & (b1 >= 0.f) & (b2 >= 0.f)) {
                        pass = true; g0 = b0; g1 = b1; g2 = b2;
                        i0 = __float_as_int(r3.y); i1 = __float_as_int(r3.z); i2 = __float_as_int(r3.w);
                    }
                }
            }
            const unsigned long long hm = __ballot(pass);
            if (hm) {
                if (lane == (int)__builtin_ctzll(hm)) {   // lowest index = ref argmax
                    const int o = pid * 3;
                    out[o + 0] = g0 * attr[3 * i0 + 0] + g1 * attr[3 * i1 + 0] + g2 * attr[3 * i2 + 0];
                    out[o + 1] = g0 * attr[3 * i0 + 1] + g1 * attr[3 * i1 + 1] + g2 * attr[3 * i2 + 1];
                    out[o + 2] = g0 * attr[3 * i0 + 2] + g1 * attr[3 * i1 + 2] + g2 * attr[3 * i2 + 2];
                }
                found = true;
            }
        }
        if (!found && lane == 0) {
            const int o = pid * 3;
            out[o + 0] = 0.f; out[o + 1] = 0.f; out[o + 2] = 0.f;
        }
    }
}

// ---- fallback (tiny workspace / huge nTri): proven-correct wave-per-pixel scan ----
__global__ __launch_bounds__(256) void bake_wave(
    const float* __restrict__ uv, const int* __restrict__ faces,
    const float* __restrict__ attr, float* __restrict__ out,
    int res, int nTri)
{
    const int lane = threadIdx.x & 63;
    const int wid  = blockIdx.x * (blockDim.x >> 6) + (threadIdx.x >> 6);
    const int npix = res * res;
    if (wid >= npix) return;
    const int pyi = wid / res, pxi = wid - pyi * res;
    const float rf = (float)res;
    const float px = ((float)pxi + 0.5f) / rf, py = ((float)pyi + 0.5f) / rf;
    for (int base = 0; base < nTri; base += 64) {
        const int t = base + lane;
        bool hit = false; float b0 = 0, b1 = 0, b2 = 0; int i0 = 0, i1 = 0, i2 = 0;
        if (t < nTri) {
            i0 = faces[3 * t]; i1 = faces[3 * t + 1]; i2 = faces[3 * t + 2];
            const float ax = uv[2 * i0], ay = uv[2 * i0 + 1];
            const float bx = uv[2 * i1], by = uv[2 * i1 + 1];
            const float cx = uv[2 * i2], cy = uv[2 * i2 + 1];
            const float area = (bx - ax) * (cy - ay) - (by - ay) * (cx - ax);
            if (fabsf(area) > 1e-9f) {
                const float inv = 1.0f / area;
                b0 = ((cx - bx) * (py - by) - (cy - by) * (px - bx)) * inv;
                b1 = ((ax - cx) * (py - cy) - (ay - cy) * (px - cx)) * inv;
                b2 = ((bx - ax) * (py - ay) - (by - ay) * (px - ax)) * inv;
                hit = (b0 >= 0.f) & (b1 >= 0.f) & (b2 >= 0.f);
            }
        }
        const unsigned long long m = __ballot(hit);
        if (m) {
            const int src = (int)__builtin_ctzll(m);
            b0 = __shfl(b0, src, 64); b1 = __shfl(b1, src, 64); b2 = __shfl(b2, src, 64);
            const int J0 = __shfl(i0, src, 64), J1 = __shfl(i1, src, 64), J2 = __shfl(i2, src, 64);
            if (lane == 0) {
                const int o = wid * 3;
                out[o + 0] = b0 * attr[3 * J0] + b1 * attr[3 * J1] + b2 * attr[3 * J2];
                out[o + 1] = b0 * attr[3 * J0 + 1] + b1 * attr[3 * J1 + 1] + b2 * attr[3 * J2 + 1];
                out[o + 2] = b0 * attr[3 * J0 + 2] + b1 * attr[3 * J1 + 2] + b2 * attr[3 * J2 + 2];
            }
            return;
        }
    }
    if (lane == 0) { const int o = wid * 3; out[o] = 0.f; out[o + 1] = 0.f; out[o + 2] = 0.f; }
}

extern "C" void kernel_launch(void* const* d_in, const int* in_sizes, int n_in,
                              void* d_out, int out_size, void* d_ws, size_t ws_size,
                              hipStream_t stream) {
    const float* attr  = (const float*)d_in[0];
    const float* uv    = (const float*)d_in[1];
    const int*   faces = (const int*)d_in[2];
    float*       out   = (float*)d_out;

    const int nTri = in_sizes[2] / 3;
    const int res  = (int)(sqrt((double)(out_size / 3)) + 0.5);
    const int npix = res * res;

    const int nCellX = (res + CELLPX - 1) / CELLPX;
    const int nCells = nCellX * nCellX;

    const size_t recsB = (size_t)nTri * 64;
    const size_t cntB  = (size_t)nCells * sizeof(int);
    const size_t listB = (size_t)nCells * LCAP * sizeof(unsigned short);
    const size_t need  = recsB + cntB + listB;   // 1,573,888 B at 8192 tris / 512 res (proven)

    if (nTri <= 65535 && ws_size >= need) {
        char* p = (char*)d_ws;
        float* recs = (float*)p;                    p += recsB;
        int* counts = (int*)p;                      p += cntB;
        unsigned short* lists = (unsigned short*)p;

        unsigned M = 1;
        while (M < (unsigned)npix) M <<= 1;
        const int nWaves = (int)(M / 64u);
        const int rblocks = (nWaves + 3) / 4;

        prep<<<(nTri + 255) / 256, 256, 0, stream>>>(uv, faces, recs, nTri);
        bin32<<<nCells, 1024, 0, stream>>>(recs, lists, counts, res, nTri, nCellX);
        dim3 grid((res + TILE - 1) / TILE, (res + TILE - 1) / TILE);
        bake16<<<grid, 256, 0, stream>>>(recs, lists, counts, attr, out, res, nTri, nCellX);
        rescue<<<rblocks, 256, 0, stream>>>(recs, lists, counts, attr, out,
                                            res, nTri, nCellX, npix, M);
    } else {
        bake_wave<<<(npix + 3) / 4, 256, 0, stream>>>(uv, faces, attr, out, res, nTri);
    }
}

// Round 11
// 67.823 us; speedup vs baseline: 1.7440x; 1.4189x over previous
//
#include <hip/hip_runtime.h>
#include <math.h>

#pragma clang fp contract(off)

#define TILE 16
#define CELLPX 32
#define LCAP 2048      // per-cell ordered list capacity (u16); overflow -> raw-order scan
#define MAXS 128       // stage-1 scan depth = one LDS batch
#define SENTU 0x7FC0DEADu   // NaN payload: impossible as a real output (outputs are finite)

// rec (16 dwords): [0]=bx [1]=by [2]=cx-bx [3]=cy-by | [4]=cx [5]=cy [6]=ax-cx [7]=ay-cy
//                  [8]=ax [9]=ay [10]=bx-ax [11]=by-ay | [12]=inv(0 if invalid) [13..15]=i0,i1,i2
__global__ __launch_bounds__(256) void prep(
    const float* __restrict__ uv, const int* __restrict__ faces,
    float* __restrict__ recs, int nTri)
{
    const int f = blockIdx.x * 256 + threadIdx.x;
    if (f >= nTri) return;
    const int i0 = faces[3 * f], i1 = faces[3 * f + 1], i2 = faces[3 * f + 2];
    const float ax = uv[2 * i0], ay = uv[2 * i0 + 1];
    const float bx = uv[2 * i1], by = uv[2 * i1 + 1];
    const float cx = uv[2 * i2], cy = uv[2 * i2 + 1];
    const float area = (bx - ax) * (cy - ay) - (by - ay) * (cx - ax);  // exact ref op
    const bool valid = fabsf(area) > 1e-9f;
    float* r = recs + 16 * f;
    r[0] = bx; r[1] = by; r[2]  = cx - bx; r[3]  = cy - by;
    r[4] = cx; r[5] = cy; r[6]  = ax - cx; r[7]  = ay - cy;
    r[8] = ax; r[9] = ay; r[10] = bx - ax; r[11] = by - ay;
    r[12] = valid ? 1.0f / area : 0.f;
    ((int*)r)[13] = i0; ((int*)r)[14] = i1; ((int*)r)[15] = i2;
}

__device__ __forceinline__ bool edgeMayPass(
    float qx, float qy, float ex, float ey, float s,
    float rx0, float rx1, float ry0, float ry1)
{
    const float A = s * ex;
    const float B = -s * ey;
    const float fy = A * ((A >= 0.f ? ry1 : ry0) - qy);
    const float fx = B * ((B >= 0.f ? rx1 : rx0) - qx);
    return (fy + fx) >= -1e-5f;   // conservative margin >> fp eval error
}

__device__ __forceinline__ bool satKeep(
    const float4 r0, const float4 r1, const float4 r2, const float inv,
    float rx0, float rx1, float ry0, float ry1)
{
    if (inv == 0.f) return false;
    const float xmn = fminf(r2.x, fminf(r0.x, r1.x));
    const float xmx = fmaxf(r2.x, fmaxf(r0.x, r1.x));
    const float ymn = fminf(r2.y, fminf(r0.y, r1.y));
    const float ymx = fmaxf(r2.y, fmaxf(r0.y, r1.y));
    if (!((xmn <= rx1) & (xmx >= rx0) & (ymn <= ry1) & (ymx >= ry0))) return false;
    const float s = (inv >= 0.f) ? 1.f : -1.f;
    return edgeMayPass(r0.x, r0.y, r0.z, r0.w, s, rx0, rx1, ry0, ry1)
        && edgeMayPass(r1.x, r1.y, r1.z, r1.w, s, rx0, rx1, ry0, ry1)
        && edgeMayPass(r2.x, r2.y, r2.z, r2.w, s, rx0, rx1, ry0, ry1);
}

// One 1024-thread block per 32px cell; index-order scan -> globally ordered list.
__global__ __launch_bounds__(1024) void bin32(
    const float* __restrict__ recs, unsigned short* __restrict__ lists,
    int* __restrict__ counts, int res, int nTri, int nCellX)
{
    __shared__ int waveCnt[16];
    const int cell = blockIdx.x;
    const int cellX = cell % nCellX, cellY = cell / nCellX;
    const float rf = (float)res;
    const float rx0 = ((float)(cellX * CELLPX) - 1.5f) / rf;
    const float rx1 = ((float)(cellX * CELLPX + CELLPX) + 1.5f) / rf;
    const float ry0 = ((float)(cellY * CELLPX) - 1.5f) / rf;
    const float ry1 = ((float)(cellY * CELLPX + CELLPX) + 1.5f) / rf;

    const int lane = threadIdx.x & 63, wv = threadIdx.x >> 6;
    unsigned short* myList = lists + (size_t)cell * LCAP;

    int cnt = 0;
    for (int base = 0; base < nTri; base += 1024) {
        const int t = base + threadIdx.x;
        bool keep = false;
        if (t < nTri) {
            const float4* R = (const float4*)(recs + 16 * t);   // coalesced 64B/lane
            const float4 r0 = R[0], r1 = R[1], r2 = R[2], r3 = R[3];
            keep = satKeep(r0, r1, r2, r3.x, rx0, rx1, ry0, ry1);
        }
        const unsigned long long m = __ballot(keep);
        if (lane == 0) waveCnt[wv] = __popcll(m);
        __syncthreads();
        int off = 0, tot = 0;
        #pragma unroll
        for (int w = 0; w < 16; ++w) {
            if (w < wv) off += waveCnt[w];
            tot += waveCnt[w];
        }
        const int pre = __popcll(m & ((1ull << lane) - 1ull));
        if (keep) {
            const int slot = cnt + off + pre;
            if (slot < LCAP) myList[slot] = (unsigned short)t;
        }
        __syncthreads();
        cnt += tot;   // > LCAP => raw-order mode (central cells: shallow hits anyway)
    }
    if (threadIdx.x == 0) counts[cell] = cnt;
}

// Stage 1: one 16px tile per block, EXACTLY one 128-candidate LDS batch, scanned
// with a depth-1 ping-pong register pipeline (loads pinned before VALU by
// sched_barrier so LDS latency hides under the previous group's tests).
__global__ __launch_bounds__(256) void bake16(
    const float* __restrict__ recs, const unsigned short* __restrict__ lists,
    const int* __restrict__ counts, const float* __restrict__ attr,
    float* __restrict__ out, int res, int nTri, int nCellX)
{
    __shared__ float4 L0[MAXS], L1[MAXS], L2[MAXS], L3[MAXS];
    __shared__ unsigned long long smask[4];

    const int tx = threadIdx.x & 15, ty = threadIdx.x >> 4;
    const int pxi = blockIdx.x * TILE + tx;
    const int pyi = blockIdx.y * TILE + ty;
    const bool inb = (pxi < res) && (pyi < res);
    const float rf = (float)res;
    const float px = ((float)pxi + 0.5f) / rf;   // exact reference op
    const float py = ((float)pyi + 0.5f) / rf;

    const int cell = ((blockIdx.y * TILE) / CELLPX) * nCellX + (blockIdx.x * TILE) / CELLPX;
    const int count = counts[cell];              // uniform
    const bool useList = (count <= LCAP);
    const int total = useList ? count : nTri;
    const int n = min(MAXS, total);
    const unsigned short* myList = lists + (size_t)cell * LCAP;

    const int lane = threadIdx.x & 63, wv = threadIdx.x >> 6;

    // ---- fill one batch + sign-of-inv mask ----
    bool sb = false;
    if (threadIdx.x < n) {
        const int t = useList ? (int)myList[threadIdx.x] : threadIdx.x;
        const float4* R = (const float4*)(recs + 16 * t);
        float4 r0 = R[0];
        const float4 r1 = R[1], r2 = R[2], r3 = R[3];
        sb = (__float_as_uint(r3.x) >> 31) != 0;
        if (r3.x == 0.f)   // invalid tri (raw mode): poison edge0 -> never passes
            r0 = make_float4(0.f, __builtin_huge_valf(), 1.f, 0.f);
        L0[threadIdx.x] = r0; L1[threadIdx.x] = r1;
        L2[threadIdx.x] = r2; L3[threadIdx.x] = r3;
    }
    const unsigned long long bal = __ballot(sb);
    if (lane == 0) smask[wv] = bal;
    __syncthreads();
    const unsigned long long m0 = smask[0], m1 = smask[1];

    // pass test: b>=0  <=>  w==0 or signbit(w)==signbit(inv)
    auto passf = [&](const float4 T0, const float4 T1, const float4 T2,
                     unsigned sv) -> unsigned {
        const float w0 = T0.z * (py - T0.y) - T0.w * (px - T0.x);
        const float w1 = T1.z * (py - T1.y) - T1.w * (px - T1.x);
        const float w2 = T2.z * (py - T2.y) - T2.w * (px - T2.x);
        const bool c0 = (w0 == 0.f) | ((__float_as_uint(w0) >> 31) == sv);
        const bool c1 = (w1 == 0.f) | ((__float_as_uint(w1) >> 31) == sv);
        const bool c2 = (w2 == 0.f) | ((__float_as_uint(w2) >> 31) == sv);
        return (unsigned)(c0 & c1 & c2);
    };

    bool hit = false;
    int kWin = 0;

    if (inb && n > 0) {
        const int last = n - 1;
        float4 pA0, pA1, pA2, pB0, pB1, pB2, pC0, pC1, pC2, pD0, pD1, pD2;
        float4 qA0, qA1, qA2, qB0, qB1, qB2, qC0, qC1, qC2, qD0, qD1, qD2;

        #define LOADSET(V, BASE)                                                 \
            { const int _ka = min((BASE), last),     _kb = min((BASE) + 1, last),\
                        _kc = min((BASE) + 2, last), _kd = min((BASE) + 3, last);\
              V##A0 = L0[_ka]; V##A1 = L1[_ka]; V##A2 = L2[_ka];                 \
              V##B0 = L0[_kb]; V##B1 = L1[_kb]; V##B2 = L2[_kb];                 \
              V##C0 = L0[_kc]; V##C1 = L1[_kc]; V##C2 = L2[_kc];                 \
              V##D0 = L0[_kd]; V##D1 = L1[_kd]; V##D2 = L2[_kd]; }

        #define TESTSET(V, BASE)                                                 \
            if (!hit) {                                                          \
                const int _ka = min((BASE), last),     _kb = min((BASE) + 1, last),\
                          _kc = min((BASE) + 2, last), _kd = min((BASE) + 3, last);\
                const unsigned long long mw = ((BASE) & 64) ? m1 : m0;           \
                unsigned pm = 0u;                                                \
                pm |= passf(V##A0, V##A1, V##A2,                                 \
                            (unsigned)((mw >> (_ka & 63)) & 1ull)) << 0;         \
                pm |= passf(V##B0, V##B1, V##B2,                                 \
                            (unsigned)((mw >> (_kb & 63)) & 1ull)) << 1;         \
                pm |= passf(V##C0, V##C1, V##C2,                                 \
                            (unsigned)((mw >> (_kc & 63)) & 1ull)) << 2;         \
                pm |= passf(V##D0, V##D1, V##D2,                                 \
                            (unsigned)((mw >> (_kd & 63)) & 1ull)) << 3;         \
                if (pm) { hit = true;                                            \
                          kWin = min((BASE) + (int)__builtin_ctz(pm), last); }   \
            }

        LOADSET(p, 0)
        for (int i = 0; i < n && !hit; i += 8) {
            LOADSET(q, i + 4)
            __builtin_amdgcn_sched_barrier(0);   // loads issued BEFORE p-tests
            TESTSET(p, i)
            LOADSET(p, i + 8)
            __builtin_amdgcn_sched_barrier(0);   // loads issued BEFORE q-tests
            TESTSET(q, i + 4)
        }
        #undef LOADSET
        #undef TESTSET
    }

    if (inb) {
        const int o = (pyi * res + pxi) * 3;
        if (hit) {   // recompute exact reference barycentrics for the winner
            const float4 E0 = L0[kWin], E1 = L1[kWin], E2 = L2[kWin], E3 = L3[kWin];
            const float w0 = E0.z * (py - E0.y) - E0.w * (px - E0.x);
            const float w1 = E1.z * (py - E1.y) - E1.w * (px - E1.x);
            const float w2 = E2.z * (py - E2.y) - E2.w * (px - E2.x);
            const float iv = E3.x;
            const float g0 = w0 * iv, g1 = w1 * iv, g2 = w2 * iv;
            const int j0 = __float_as_int(E3.y), j1 = __float_as_int(E3.z), j2 = __float_as_int(E3.w);
            out[o + 0] = g0 * attr[3 * j0 + 0] + g1 * attr[3 * j1 + 0] + g2 * attr[3 * j2 + 0];
            out[o + 1] = g0 * attr[3 * j0 + 1] + g1 * attr[3 * j1 + 1] + g2 * attr[3 * j2 + 1];
            out[o + 2] = g0 * attr[3 * j0 + 2] + g1 * attr[3 * j1 + 2] + g2 * attr[3 * j2 + 2];
        } else if (total <= MAXS) {      // complete list scanned: truly empty pixel
            out[o + 0] = 0.f; out[o + 1] = 0.f; out[o + 2] = 0.f;
        } else {                         // defer to stage 2
            const float s = __uint_as_float(SENTU);
            out[o + 0] = s; out[o + 1] = s; out[o + 2] = s;
        }
    }
}

// Stage 2: one wave per straggler pixel. Lanes probe hash-scattered pixels so
// boundary stragglers spread uniformly across waves; ballot-scan 64 cand/iter.
__global__ __launch_bounds__(256) void rescue(
    const float* __restrict__ recs, const unsigned short* __restrict__ lists,
    const int* __restrict__ counts, const float* __restrict__ attr,
    float* __restrict__ out, int res, int nTri, int nCellX,
    int npix, unsigned M)   // M = pow2 >= npix
{
    const int lane = threadIdx.x & 63;
    const int w = blockIdx.x * 4 + (threadIdx.x >> 6);
    const float rf = (float)res;

    const unsigned t0 = (unsigned)w * 64u + (unsigned)lane;
    if (t0 >= M) return;
    const unsigned p = (t0 * 2654435761u) & (M - 1u);   // odd mult: bijection mod 2^k
    bool sent = false;
    if (p < (unsigned)npix) sent = (__float_as_uint(out[3 * p]) == SENTU);
    unsigned long long mask = __ballot(sent);

    while (mask) {
        const int b = (int)__builtin_ctzll(mask);
        mask &= mask - 1;
        const unsigned tb = (unsigned)w * 64u + (unsigned)b;
        const int pid = (int)((tb * 2654435761u) & (M - 1u));   // uniform across wave
        const int pyi = pid / res, pxi = pid - pyi * res;
        const float px = ((float)pxi + 0.5f) / rf;
        const float py = ((float)pyi + 0.5f) / rf;
        const int cell = (pyi / CELLPX) * nCellX + pxi / CELLPX;
        const int count = counts[cell];
        const bool useList = (count <= LCAP);
        const int total = useList ? count : nTri;
        const unsigned short* myList = lists + (size_t)cell * LCAP;

        bool found = false;
        for (int base = MAXS; base < total && !found; base += 64) {
            const int idx = base + lane;
            bool pass = false;
            float g0 = 0.f, g1 = 0.f, g2 = 0.f; int i0 = 0, i1 = 0, i2 = 0;
            if (idx < total) {
                const int t = useList ? (int)myList[idx] : idx;
                const float4* R = (const float4*)(recs + 16 * t);
                const float4 r0 = R[0], r1 = R[1], r2 = R[2], r3 = R[3];
                const float iv = r3.x;
                if (iv != 0.f) {
                    const float w0 = r0.z * (py - r0.y) - r0.w * (px - r0.x);
                    const float w1 = r1.z * (py - r1.y) - r1.w * (px - r1.x);
                    const float w2 = r2.z * (py - r2.y) - r2.w * (px - r2.x);
                    const float b0 = w0 * iv, b1 = w1 * iv, b2 = w2 * iv;
                    if ((b0 >= 0.f) & (b1 >= 0.f) & (b2 >= 0.f)) {
                        pass = true; g0 = b0; g1 = b1; g2 = b2;
                        i0 = __float_as_int(r3.y); i1 = __float_as_int(r3.z); i2 = __float_as_int(r3.w);
                    }
                }
            }
            const unsigned long long hm = __ballot(pass);
            if (hm) {
                if (lane == (int)__builtin_ctzll(hm)) {   // lowest index = ref argmax
                    const int o = pid * 3;
                    out[o + 0] = g0 * attr[3 * i0 + 0] + g1 * attr[3 * i1 + 0] + g2 * attr[3 * i2 + 0];
                    out[o + 1] = g0 * attr[3 * i0 + 1] + g1 * attr[3 * i1 + 1] + g2 * attr[3 * i2 + 1];
                    out[o + 2] = g0 * attr[3 * i0 + 2] + g1 * attr[3 * i1 + 2] + g2 * attr[3 * i2 + 2];
                }
                found = true;
            }
        }
        if (!found && lane == 0) {
            const int o = pid * 3;
            out[o + 0] = 0.f; out[o + 1] = 0.f; out[o + 2] = 0.f;
        }
    }
}

// ---- fallback (tiny workspace / huge nTri): proven-correct wave-per-pixel scan ----
__global__ __launch_bounds__(256) void bake_wave(
    const float* __restrict__ uv, const int* __restrict__ faces,
    const float* __restrict__ attr, float* __restrict__ out,
    int res, int nTri)
{
    const int lane = threadIdx.x & 63;
    const int wid  = blockIdx.x * (blockDim.x >> 6) + (threadIdx.x >> 6);
    const int npix = res * res;
    if (wid >= npix) return;
    const int pyi = wid / res, pxi = wid - pyi * res;
    const float rf = (float)res;
    const float px = ((float)pxi + 0.5f) / rf, py = ((float)pyi + 0.5f) / rf;
    for (int base = 0; base < nTri; base += 64) {
        const int t = base + lane;
        bool hit = false; float b0 = 0, b1 = 0, b2 = 0; int i0 = 0, i1 = 0, i2 = 0;
        if (t < nTri) {
            i0 = faces[3 * t]; i1 = faces[3 * t + 1]; i2 = faces[3 * t + 2];
            const float ax = uv[2 * i0], ay = uv[2 * i0 + 1];
            const float bx = uv[2 * i1], by = uv[2 * i1 + 1];
            const float cx = uv[2 * i2], cy = uv[2 * i2 + 1];
            const float area = (bx - ax) * (cy - ay) - (by - ay) * (cx - ax);
            if (fabsf(area) > 1e-9f) {
                const float inv = 1.0f / area;
                b0 = ((cx - bx) * (py - by) - (cy - by) * (px - bx)) * inv;
                b1 = ((ax - cx) * (py - cy) - (ay - cy) * (px - cx)) * inv;
                b2 = ((bx - ax) * (py - ay) - (by - ay) * (px - ax)) * inv;
                hit = (b0 >= 0.f) & (b1 >= 0.f) & (b2 >= 0.f);
            }
        }
        const unsigned long long m = __ballot(hit);
        if (m) {
            const int src = (int)__builtin_ctzll(m);
            b0 = __shfl(b0, src, 64); b1 = __shfl(b1, src, 64); b2 = __shfl(b2, src, 64);
            const int J0 = __shfl(i0, src, 64), J1 = __shfl(i1, src, 64), J2 = __shfl(i2, src, 64);
            if (lane == 0) {
                const int o = wid * 3;
                out[o + 0] = b0 * attr[3 * J0] + b1 * attr[3 * J1] + b2 * attr[3 * J2];
                out[o + 1] = b0 * attr[3 * J0 + 1] + b1 * attr[3 * J1 + 1] + b2 * attr[3 * J2 + 1];
                out[o + 2] = b0 * attr[3 * J0 + 2] + b1 * attr[3 * J1 + 2] + b2 * attr[3 * J2 + 2];
            }
            return;
        }
    }
    if (lane == 0) { const int o = wid * 3; out[o] = 0.f; out[o + 1] = 0.f; out[o + 2] = 0.f; }
}

extern "C" void kernel_launch(void* const* d_in, const int* in_sizes, int n_in,
                              void* d_out, int out_size, void* d_ws, size_t ws_size,
                              hipStream_t stream) {
    const float* attr  = (const float*)d_in[0];
    const float* uv    = (const float*)d_in[1];
    const int*   faces = (const int*)d_in[2];
    float*       out   = (float*)d_out;

    const int nTri = in_sizes[2] / 3;
    const int res  = (int)(sqrt((double)(out_size / 3)) + 0.5);
    const int npix = res * res;

    const int nCellX = (res + CELLPX - 1) / CELLPX;
    const int nCells = nCellX * nCellX;

    const size_t recsB = (size_t)nTri * 64;
    const size_t cntB  = (size_t)nCells * sizeof(int);
    const size_t listB = (size_t)nCells * LCAP * sizeof(unsigned short);
    const size_t need  = recsB + cntB + listB;   // 1,573,888 B at 8192 tris / 512 res (proven)

    if (nTri <= 65535 && ws_size >= need) {
        char* p = (char*)d_ws;
        float* recs = (float*)p;                    p += recsB;
        int* counts = (int*)p;                      p += cntB;
        unsigned short* lists = (unsigned short*)p;

        unsigned M = 1;
        while (M < (unsigned)npix) M <<= 1;
        const int nWaves = (int)(M / 64u);
        const int rblocks = (nWaves + 3) / 4;

        prep<<<(nTri + 255) / 256, 256, 0, stream>>>(uv, faces, recs, nTri);
        bin32<<<nCells, 1024, 0, stream>>>(recs, lists, counts, res, nTri, nCellX);
        dim3 grid((res + TILE - 1) / TILE, (res + TILE - 1) / TILE);
        bake16<<<grid, 256, 0, stream>>>(recs, lists, counts, attr, out, res, nTri, nCellX);
        rescue<<<rblocks, 256, 0, stream>>>(recs, lists, counts, attr, out,
                                            res, nTri, nCellX, npix, M);
    } else {
        bake_wave<<<(npix + 3) / 4, 256, 0, stream>>>(uv, faces, attr, out, res, nTri);
    }
}

// Round 12
// 62.260 us; speedup vs baseline: 1.8998x; 1.0893x over previous
//
#include <hip/hip_runtime.h>
#include <math.h>

#pragma clang fp contract(off)

#define TILE 16
#define CELLPX 32
#define LCAP 2048      // per-cell ordered list capacity (u16); overflow -> raw-order scan
#define MAXS 128       // stage-1 scan depth = one LDS batch

// rec (16 dwords): [0]=bx [1]=by [2]=cx-bx [3]=cy-by | [4]=cx [5]=cy [6]=ax-cx [7]=ay-cy
//                  [8]=ax [9]=ay [10]=bx-ax [11]=by-ay | [12]=inv(0 if invalid) [13..15]=i0,i1,i2
__global__ __launch_bounds__(256) void prep(
    const float* __restrict__ uv, const int* __restrict__ faces,
    float* __restrict__ recs, int* __restrict__ qCount, int nTri)
{
    if (blockIdx.x == 0 && threadIdx.x == 0) *qCount = 0;   // re-zeroed every replay
    const int f = blockIdx.x * 256 + threadIdx.x;
    if (f >= nTri) return;
    const int i0 = faces[3 * f], i1 = faces[3 * f + 1], i2 = faces[3 * f + 2];
    const float ax = uv[2 * i0], ay = uv[2 * i0 + 1];
    const float bx = uv[2 * i1], by = uv[2 * i1 + 1];
    const float cx = uv[2 * i2], cy = uv[2 * i2 + 1];
    const float area = (bx - ax) * (cy - ay) - (by - ay) * (cx - ax);  // exact ref op
    const bool valid = fabsf(area) > 1e-9f;
    float* r = recs + 16 * f;
    r[0] = bx; r[1] = by; r[2]  = cx - bx; r[3]  = cy - by;
    r[4] = cx; r[5] = cy; r[6]  = ax - cx; r[7]  = ay - cy;
    r[8] = ax; r[9] = ay; r[10] = bx - ax; r[11] = by - ay;
    r[12] = valid ? 1.0f / area : 0.f;
    ((int*)r)[13] = i0; ((int*)r)[14] = i1; ((int*)r)[15] = i2;
}

__device__ __forceinline__ bool edgeMayPass(
    float qx, float qy, float ex, float ey, float s,
    float rx0, float rx1, float ry0, float ry1)
{
    const float A = s * ex;
    const float B = -s * ey;
    const float fy = A * ((A >= 0.f ? ry1 : ry0) - qy);
    const float fx = B * ((B >= 0.f ? rx1 : rx0) - qx);
    return (fy + fx) >= -1e-5f;   // conservative margin >> fp eval error
}

__device__ __forceinline__ bool satKeep(
    const float4 r0, const float4 r1, const float4 r2, const float inv,
    float rx0, float rx1, float ry0, float ry1)
{
    if (inv == 0.f) return false;
    const float xmn = fminf(r2.x, fminf(r0.x, r1.x));
    const float xmx = fmaxf(r2.x, fmaxf(r0.x, r1.x));
    const float ymn = fminf(r2.y, fminf(r0.y, r1.y));
    const float ymx = fmaxf(r2.y, fmaxf(r0.y, r1.y));
    if (!((xmn <= rx1) & (xmx >= rx0) & (ymn <= ry1) & (ymx >= ry0))) return false;
    const float s = (inv >= 0.f) ? 1.f : -1.f;
    return edgeMayPass(r0.x, r0.y, r0.z, r0.w, s, rx0, rx1, ry0, ry1)
        && edgeMayPass(r1.x, r1.y, r1.z, r1.w, s, rx0, rx1, ry0, ry1)
        && edgeMayPass(r2.x, r2.y, r2.z, r2.w, s, rx0, rx1, ry0, ry1);
}

// One 1024-thread block per 32px cell; index-order scan -> globally ordered list.
__global__ __launch_bounds__(1024) void bin32(
    const float* __restrict__ recs, unsigned short* __restrict__ lists,
    int* __restrict__ counts, int res, int nTri, int nCellX)
{
    __shared__ int waveCnt[16];
    const int cell = blockIdx.x;
    const int cellX = cell % nCellX, cellY = cell / nCellX;
    const float rf = (float)res;
    const float rx0 = ((float)(cellX * CELLPX) - 1.5f) / rf;
    const float rx1 = ((float)(cellX * CELLPX + CELLPX) + 1.5f) / rf;
    const float ry0 = ((float)(cellY * CELLPX) - 1.5f) / rf;
    const float ry1 = ((float)(cellY * CELLPX + CELLPX) + 1.5f) / rf;

    const int lane = threadIdx.x & 63, wv = threadIdx.x >> 6;
    unsigned short* myList = lists + (size_t)cell * LCAP;

    int cnt = 0;
    for (int base = 0; base < nTri; base += 1024) {
        const int t = base + threadIdx.x;
        bool keep = false;
        if (t < nTri) {
            const float4* R = (const float4*)(recs + 16 * t);   // coalesced 64B/lane
            const float4 r0 = R[0], r1 = R[1], r2 = R[2], r3 = R[3];
            keep = satKeep(r0, r1, r2, r3.x, rx0, rx1, ry0, ry1);
        }
        const unsigned long long m = __ballot(keep);
        if (lane == 0) waveCnt[wv] = __popcll(m);
        __syncthreads();
        int off = 0, tot = 0;
        #pragma unroll
        for (int w = 0; w < 16; ++w) {
            if (w < wv) off += waveCnt[w];
            tot += waveCnt[w];
        }
        const int pre = __popcll(m & ((1ull << lane) - 1ull));
        if (keep) {
            const int slot = cnt + off + pre;
            if (slot < LCAP) myList[slot] = (unsigned short)t;
        }
        __syncthreads();
        cnt += tot;   // > LCAP => raw-order mode (central cells: shallow hits anyway)
    }
    if (threadIdx.x == 0) counts[cell] = cnt;
}

// Stage 1: one 16px tile per block, EXACTLY one 128-candidate LDS batch, scanned
// with a depth-1 ping-pong register pipeline. Unresolved pixels with deeper
// lists are pushed to a compact queue (wave-aggregated atomicAdd).
__global__ __launch_bounds__(256) void bake16(
    const float* __restrict__ recs, const unsigned short* __restrict__ lists,
    const int* __restrict__ counts, const float* __restrict__ attr,
    float* __restrict__ out, unsigned* __restrict__ queue, int* __restrict__ qCount,
    int res, int nTri, int nCellX)
{
    __shared__ float4 L0[MAXS], L1[MAXS], L2[MAXS], L3[MAXS];
    __shared__ unsigned long long smask[4];

    const int tx = threadIdx.x & 15, ty = threadIdx.x >> 4;
    const int pxi = blockIdx.x * TILE + tx;
    const int pyi = blockIdx.y * TILE + ty;
    const bool inb = (pxi < res) && (pyi < res);
    const float rf = (float)res;
    const float px = ((float)pxi + 0.5f) / rf;   // exact reference op
    const float py = ((float)pyi + 0.5f) / rf;

    const int cell = ((blockIdx.y * TILE) / CELLPX) * nCellX + (blockIdx.x * TILE) / CELLPX;
    const int count = counts[cell];              // uniform
    const bool useList = (count <= LCAP);
    const int total = useList ? count : nTri;
    const int n = min(MAXS, total);
    const unsigned short* myList = lists + (size_t)cell * LCAP;

    const int lane = threadIdx.x & 63, wv = threadIdx.x >> 6;

    // ---- fill one batch + sign-of-inv mask ----
    bool sb = false;
    if (threadIdx.x < n) {
        const int t = useList ? (int)myList[threadIdx.x] : threadIdx.x;
        const float4* R = (const float4*)(recs + 16 * t);
        float4 r0 = R[0];
        const float4 r1 = R[1], r2 = R[2], r3 = R[3];
        sb = (__float_as_uint(r3.x) >> 31) != 0;
        if (r3.x == 0.f)   // invalid tri (raw mode): poison edge0 -> never passes
            r0 = make_float4(0.f, __builtin_huge_valf(), 1.f, 0.f);
        L0[threadIdx.x] = r0; L1[threadIdx.x] = r1;
        L2[threadIdx.x] = r2; L3[threadIdx.x] = r3;
    }
    const unsigned long long bal = __ballot(sb);
    if (lane == 0) smask[wv] = bal;
    __syncthreads();
    const unsigned long long m0 = smask[0], m1 = smask[1];

    // pass test: b>=0  <=>  w==0 or signbit(w)==signbit(inv)
    auto passf = [&](const float4 T0, const float4 T1, const float4 T2,
                     unsigned sv) -> unsigned {
        const float w0 = T0.z * (py - T0.y) - T0.w * (px - T0.x);
        const float w1 = T1.z * (py - T1.y) - T1.w * (px - T1.x);
        const float w2 = T2.z * (py - T2.y) - T2.w * (px - T2.x);
        const bool c0 = (w0 == 0.f) | ((__float_as_uint(w0) >> 31) == sv);
        const bool c1 = (w1 == 0.f) | ((__float_as_uint(w1) >> 31) == sv);
        const bool c2 = (w2 == 0.f) | ((__float_as_uint(w2) >> 31) == sv);
        return (unsigned)(c0 & c1 & c2);
    };

    bool hit = false;
    int kWin = 0;

    if (inb && n > 0) {
        const int last = n - 1;
        float4 pA0, pA1, pA2, pB0, pB1, pB2, pC0, pC1, pC2, pD0, pD1, pD2;
        float4 qA0, qA1, qA2, qB0, qB1, qB2, qC0, qC1, qC2, qD0, qD1, qD2;

        #define LOADSET(V, BASE)                                                 \
            { const int _ka = min((BASE), last),     _kb = min((BASE) + 1, last),\
                        _kc = min((BASE) + 2, last), _kd = min((BASE) + 3, last);\
              V##A0 = L0[_ka]; V##A1 = L1[_ka]; V##A2 = L2[_ka];                 \
              V##B0 = L0[_kb]; V##B1 = L1[_kb]; V##B2 = L2[_kb];                 \
              V##C0 = L0[_kc]; V##C1 = L1[_kc]; V##C2 = L2[_kc];                 \
              V##D0 = L0[_kd]; V##D1 = L1[_kd]; V##D2 = L2[_kd]; }

        #define TESTSET(V, BASE)                                                 \
            if (!hit) {                                                          \
                const int _ka = min((BASE), last),     _kb = min((BASE) + 1, last),\
                          _kc = min((BASE) + 2, last), _kd = min((BASE) + 3, last);\
                const unsigned long long mw = ((BASE) & 64) ? m1 : m0;           \
                unsigned pm = 0u;                                                \
                pm |= passf(V##A0, V##A1, V##A2,                                 \
                            (unsigned)((mw >> (_ka & 63)) & 1ull)) << 0;         \
                pm |= passf(V##B0, V##B1, V##B2,                                 \
                            (unsigned)((mw >> (_kb & 63)) & 1ull)) << 1;         \
                pm |= passf(V##C0, V##C1, V##C2,                                 \
                            (unsigned)((mw >> (_kc & 63)) & 1ull)) << 2;         \
                pm |= passf(V##D0, V##D1, V##D2,                                 \
                            (unsigned)((mw >> (_kd & 63)) & 1ull)) << 3;         \
                if (pm) { hit = true;                                            \
                          kWin = min((BASE) + (int)__builtin_ctz(pm), last); }   \
            }

        LOADSET(p, 0)
        for (int i = 0; i < n && !hit; i += 8) {
            LOADSET(q, i + 4)
            __builtin_amdgcn_sched_barrier(0);   // loads issued BEFORE p-tests
            TESTSET(p, i)
            LOADSET(p, i + 8)
            __builtin_amdgcn_sched_barrier(0);   // loads issued BEFORE q-tests
            TESTSET(q, i + 4)
        }
        #undef LOADSET
        #undef TESTSET
    }

    if (inb && hit) {   // recompute exact reference barycentrics for the winner
        const int o = (pyi * res + pxi) * 3;
        const float4 E0 = L0[kWin], E1 = L1[kWin], E2 = L2[kWin], E3 = L3[kWin];
        const float w0 = E0.z * (py - E0.y) - E0.w * (px - E0.x);
        const float w1 = E1.z * (py - E1.y) - E1.w * (px - E1.x);
        const float w2 = E2.z * (py - E2.y) - E2.w * (px - E2.x);
        const float iv = E3.x;
        const float g0 = w0 * iv, g1 = w1 * iv, g2 = w2 * iv;
        const int j0 = __float_as_int(E3.y), j1 = __float_as_int(E3.z), j2 = __float_as_int(E3.w);
        out[o + 0] = g0 * attr[3 * j0 + 0] + g1 * attr[3 * j1 + 0] + g2 * attr[3 * j2 + 0];
        out[o + 1] = g0 * attr[3 * j0 + 1] + g1 * attr[3 * j1 + 1] + g2 * attr[3 * j2 + 1];
        out[o + 2] = g0 * attr[3 * j0 + 2] + g1 * attr[3 * j1 + 2] + g2 * attr[3 * j2 + 2];
    } else if (inb && total <= MAXS) {   // complete list scanned: truly empty pixel
        const int o = (pyi * res + pxi) * 3;
        out[o + 0] = 0.f; out[o + 1] = 0.f; out[o + 2] = 0.f;
    }

    // ---- defer unresolved pixels: wave-aggregated queue push ----
    // (queue ORDER is nondeterministic; per-pixel processing & output are not)
    const bool defer = inb && !hit && (total > MAXS);
    const unsigned long long dm = __ballot(defer);
    if (dm) {
        const int leader = (int)__builtin_ctzll(dm);
        int base = 0;
        if (lane == leader) base = atomicAdd(qCount, __popcll(dm));
        base = __shfl(base, leader, 64);
        if (defer) {
            const int pre = __popcll(dm & ((1ull << lane) - 1ull));
            queue[base + pre] = (unsigned)(pyi * res + pxi);
        }
    }
}

// Stage 2: one wave per queued straggler (grid-stride). Ballot-scan the list
// tail 64 candidates/iter; lowest passing lane = reference argmax.
__global__ __launch_bounds__(256) void rescue(
    const float* __restrict__ recs, const unsigned short* __restrict__ lists,
    const int* __restrict__ counts, const float* __restrict__ attr,
    float* __restrict__ out, const unsigned* __restrict__ queue,
    const int* __restrict__ qCount, int res, int nTri, int nCellX)
{
    const int lane = threadIdx.x & 63;
    const int wid  = blockIdx.x * 4 + (threadIdx.x >> 6);
    const int nW   = gridDim.x * 4;
    const float rf = (float)res;
    const int qn = *qCount;   // uniform

    for (int k = wid; k < qn; k += nW) {
        const int pid = (int)queue[k];
        const int pyi = pid / res, pxi = pid - pyi * res;
        const float px = ((float)pxi + 0.5f) / rf;
        const float py = ((float)pyi + 0.5f) / rf;
        const int cell = (pyi / CELLPX) * nCellX + pxi / CELLPX;
        const int count = counts[cell];
        const bool useList = (count <= LCAP);
        const int total = useList ? count : nTri;
        const unsigned short* myList = lists + (size_t)cell * LCAP;

        bool found = false;
        for (int base = MAXS; base < total && !found; base += 64) {
            const int idx = base + lane;
            bool pass = false;
            float g0 = 0.f, g1 = 0.f, g2 = 0.f; int i0 = 0, i1 = 0, i2 = 0;
            if (idx < total) {
                const int t = useList ? (int)myList[idx] : idx;
                const float4* R = (const float4*)(recs + 16 * t);
                const float4 r0 = R[0], r1 = R[1], r2 = R[2], r3 = R[3];
                const float iv = r3.x;
                if (iv != 0.f) {
                    const float w0 = r0.z * (py - r0.y) - r0.w * (px - r0.x);
                    const float w1 = r1.z * (py - r1.y) - r1.w * (px - r1.x);
                    const float w2 = r2.z * (py - r2.y) - r2.w * (px - r2.x);
                    const float b0 = w0 * iv, b1 = w1 * iv, b2 = w2 * iv;
                    if ((b0 >= 0.f) & (b1 >= 0.f) & (b2 >= 0.f)) {
                        pass = true; g0 = b0; g1 = b1; g2 = b2;
                        i0 = __float_as_int(r3.y); i1 = __float_as_int(r3.z); i2 = __float_as_int(r3.w);
                    }
                }
            }
            const unsigned long long hm = __ballot(pass);
            if (hm) {
                if (lane == (int)__builtin_ctzll(hm)) {   // lowest index = ref argmax
                    const int o = pid * 3;
                    out[o + 0] = g0 * attr[3 * i0 + 0] + g1 * attr[3 * i1 + 0] + g2 * attr[3 * i2 + 0];
                    out[o + 1] = g0 * attr[3 * i0 + 1] + g1 * attr[3 * i1 + 1] + g2 * attr[3 * i2 + 1];
                    out[o + 2] = g0 * attr[3 * i0 + 2] + g1 * attr[3 * i1 + 2] + g2 * attr[3 * i2 + 2];
                }
                found = true;
            }
        }
        if (!found && lane == 0) {
            const int o = pid * 3;
            out[o + 0] = 0.f; out[o + 1] = 0.f; out[o + 2] = 0.f;
        }
    }
}

// ---- fallback (tiny workspace / huge nTri): proven-correct wave-per-pixel scan ----
__global__ __launch_bounds__(256) void bake_wave(
    const float* __restrict__ uv, const int* __restrict__ faces,
    const float* __restrict__ attr, float* __restrict__ out,
    int res, int nTri)
{
    const int lane = threadIdx.x & 63;
    const int wid  = blockIdx.x * (blockDim.x >> 6) + (threadIdx.x >> 6);
    const int npix = res * res;
    if (wid >= npix) return;
    const int pyi = wid / res, pxi = wid - pyi * res;
    const float rf = (float)res;
    const float px = ((float)pxi + 0.5f) / rf, py = ((float)pyi + 0.5f) / rf;
    for (int base = 0; base < nTri; base += 64) {
        const int t = base + lane;
        bool hit = false; float b0 = 0, b1 = 0, b2 = 0; int i0 = 0, i1 = 0, i2 = 0;
        if (t < nTri) {
            i0 = faces[3 * t]; i1 = faces[3 * t + 1]; i2 = faces[3 * t + 2];
            const float ax = uv[2 * i0], ay = uv[2 * i0 + 1];
            const float bx = uv[2 * i1], by = uv[2 * i1 + 1];
            const float cx = uv[2 * i2], cy = uv[2 * i2 + 1];
            const float area = (bx - ax) * (cy - ay) - (by - ay) * (cx - ax);
            if (fabsf(area) > 1e-9f) {
                const float inv = 1.0f / area;
                b0 = ((cx - bx) * (py - by) - (cy - by) * (px - bx)) * inv;
                b1 = ((ax - cx) * (py - cy) - (ay - cy) * (px - cx)) * inv;
                b2 = ((bx - ax) * (py - ay) - (by - ay) * (px - ax)) * inv;
                hit = (b0 >= 0.f) & (b1 >= 0.f) & (b2 >= 0.f);
            }
        }
        const unsigned long long m = __ballot(hit);
        if (m) {
            const int src = (int)__builtin_ctzll(m);
            b0 = __shfl(b0, src, 64); b1 = __shfl(b1, src, 64); b2 = __shfl(b2, src, 64);
            const int J0 = __shfl(i0, src, 64), J1 = __shfl(i1, src, 64), J2 = __shfl(i2, src, 64);
            if (lane == 0) {
                const int o = wid * 3;
                out[o + 0] = b0 * attr[3 * J0] + b1 * attr[3 * J1] + b2 * attr[3 * J2];
                out[o + 1] = b0 * attr[3 * J0 + 1] + b1 * attr[3 * J1 + 1] + b2 * attr[3 * J2 + 1];
                out[o + 2] = b0 * attr[3 * J0 + 2] + b1 * attr[3 * J1 + 2] + b2 * attr[3 * J2 + 2];
            }
            return;
        }
    }
    if (lane == 0) { const int o = wid * 3; out[o] = 0.f; out[o + 1] = 0.f; out[o + 2] = 0.f; }
}

extern "C" void kernel_launch(void* const* d_in, const int* in_sizes, int n_in,
                              void* d_out, int out_size, void* d_ws, size_t ws_size,
                              hipStream_t stream) {
    const float* attr  = (const float*)d_in[0];
    const float* uv    = (const float*)d_in[1];
    const int*   faces = (const int*)d_in[2];
    float*       out   = (float*)d_out;

    const int nTri = in_sizes[2] / 3;
    const int res  = (int)(sqrt((double)(out_size / 3)) + 0.5);
    const int npix = res * res;

    const int nCellX = (res + CELLPX - 1) / CELLPX;
    const int nCells = nCellX * nCellX;

    const size_t recsB  = (size_t)nTri * 64;
    const size_t cntB   = (size_t)nCells * sizeof(int);
    const size_t listB  = (size_t)nCells * LCAP * sizeof(unsigned short);
    const size_t qcB    = 16;
    const size_t queueB = (size_t)npix * sizeof(unsigned);
    const size_t need   = recsB + cntB + listB + qcB + queueB;   // ~2.62 MB

    if (nTri <= 65535 && ws_size >= need) {
        char* p = (char*)d_ws;
        float* recs = (float*)p;                    p += recsB;
        int* counts = (int*)p;                      p += cntB;
        unsigned short* lists = (unsigned short*)p; p += listB;
        int* qCount = (int*)p;                      p += qcB;
        unsigned* queue = (unsigned*)p;

        prep<<<(nTri + 255) / 256, 256, 0, stream>>>(uv, faces, recs, qCount, nTri);
        bin32<<<nCells, 1024, 0, stream>>>(recs, lists, counts, res, nTri, nCellX);
        dim3 grid((res + TILE - 1) / TILE, (res + TILE - 1) / TILE);
        bake16<<<grid, 256, 0, stream>>>(recs, lists, counts, attr, out, queue, qCount,
                                         res, nTri, nCellX);
        rescue<<<4096, 256, 0, stream>>>(recs, lists, counts, attr, out, queue, qCount,
                                         res, nTri, nCellX);
    } else {
        bake_wave<<<(npix + 3) / 4, 256, 0, stream>>>(uv, faces, attr, out, res, nTri);
    }
}